// Round 4
// baseline (510.044 us; speedup 1.0000x reference)
//
#include <hip/hip_runtime.h>
#include <hip/hip_bf16.h>

typedef __bf16 bf16_t;
typedef __bf16 bf16x8 __attribute__((ext_vector_type(8)));
typedef __bf16 bf16x4 __attribute__((ext_vector_type(4)));
typedef float f32x4 __attribute__((ext_vector_type(4)));

#define NE 10
#define DM 512
#define SCALE_F 0.125f

// async global->LDS, 16B per lane. LDS dst is wave-uniform base + lane*16.
__device__ __forceinline__ void gl16(const void* g, void* l) {
    __builtin_amdgcn_global_load_lds(
        (const __attribute__((address_space(1))) unsigned int*)g,
        (__attribute__((address_space(3))) unsigned int*)l, 16, 0, 0);
}

// ---------------- cast fp32 -> bf16 (8 elems/thread) ----------------
__global__ void cast_bf16_kernel(const float* __restrict__ in, bf16_t* __restrict__ out, int n)
{
    const int i = (blockIdx.x * 256 + threadIdx.x) * 8;
    if (i >= n) return;
    float4 a = *(const float4*)(in + i);
    float4 b = *(const float4*)(in + i + 4);
    bf16x8 o;
    o[0] = (bf16_t)a.x; o[1] = (bf16_t)a.y; o[2] = (bf16_t)a.z; o[3] = (bf16_t)a.w;
    o[4] = (bf16_t)b.x; o[5] = (bf16_t)b.y; o[6] = (bf16_t)b.z; o[7] = (bf16_t)b.w;
    *(bf16x8*)(out + i) = o;
}

// ---------------- 4x W[e][k][n] fp32 -> Wt[which][e][n][k] bf16 (fused) ----------------
__global__ void wtrans4_kernel(const float* __restrict__ W0, const float* __restrict__ W1,
                               const float* __restrict__ W2, const float* __restrict__ W3,
                               bf16_t* __restrict__ Wt)
{
    __shared__ float tile[32][33];
    const int z = blockIdx.z, which = z / NE, e = z - which * NE;
    const float* W = which == 0 ? W0 : which == 1 ? W1 : which == 2 ? W2 : W3;
    const int n0 = blockIdx.x * 32, k0 = blockIdx.y * 32;
    const int tx = threadIdx.x & 31, ty = threadIdx.x >> 5; // ty 0..7
    const float* Wp = W + ((size_t)e * DM + k0) * DM + n0;
#pragma unroll
    for (int r = 0; r < 32; r += 8) tile[ty + r][tx] = Wp[(size_t)(ty + r) * DM + tx];
    __syncthreads();
    bf16_t* Op = Wt + (((size_t)which * NE + e) * DM + n0) * DM + k0;
#pragma unroll
    for (int r = 0; r < 32; r += 8) Op[(size_t)(ty + r) * DM + tx] = (bf16_t)tile[tx][ty + r];
}

// ---------------- top-k gate selection + renorm (fp32, matches lax.top_k ties) ----------
__device__ __forceinline__ void topk_write(const float* p, const float* __restrict__ gb,
                                           float* __restrict__ G, int t)
{
    float l[NE], ex[NE];
    float mx = -3.4e38f;
#pragma unroll
    for (int e = 0; e < NE; e++) { l[e] = p[e] + gb[e]; mx = fmaxf(mx, l[e]); }
#pragma unroll
    for (int e = 0; e < NE; e++) ex[e] = __expf(l[e] - mx);
    bool sel[NE];
#pragma unroll
    for (int e = 0; e < NE; e++) sel[e] = false;
    float ssel = 0.f;
    for (int j = 0; j < 5; j++) {
        int bi = 0; float bv = -3.4e38f;
        for (int e = 0; e < NE; e++)
            if (!sel[e] && l[e] > bv) { bv = l[e]; bi = e; }
        sel[bi] = true; ssel += ex[bi];
    }
    const float inv = 1.f / ssel;
    for (int e = 0; e < NE; e++) G[(size_t)t * NE + e] = sel[e] ? ex[e] * inv : 0.f;
}

// one 64-thread block per token
__global__ void moe_gates(const float* __restrict__ X, const float* __restrict__ gw,
                          const float* __restrict__ gb, float* __restrict__ G)
{
    const int t = blockIdx.x;
    const int lane = threadIdx.x;
    const float* x = X + (size_t)t * DM;
    float p[NE];
#pragma unroll
    for (int e = 0; e < NE; e++) p[e] = 0.f;
    for (int i = lane; i < DM; i += 64) {
        const float xv = x[i];
        const float* g = gw + (size_t)i * NE;
#pragma unroll
        for (int e = 0; e < NE; e++) p[e] += xv * g[e];
    }
#pragma unroll
    for (int off = 32; off > 0; off >>= 1)
#pragma unroll
        for (int e = 0; e < NE; e++) p[e] += __shfl_down(p[e], off);
    if (lane == 0) topk_write(p, gb, G, t);
}

// fused k+v gates: 4 waves/block, one token per wave, X read once
__global__ void moe_gates_kv(const float* __restrict__ X,
                             const float* __restrict__ kgw, const float* __restrict__ kgb,
                             const float* __restrict__ vgw, const float* __restrict__ vgb,
                             float* __restrict__ Gk, float* __restrict__ Gv)
{
    const int t = blockIdx.x * 4 + (threadIdx.x >> 6);
    const int lane = threadIdx.x & 63;
    const float* x = X + (size_t)t * DM;
    float xr[8];
    *(float4*)&xr[0] = *(const float4*)(x + lane * 8);
    *(float4*)&xr[4] = *(const float4*)(x + lane * 8 + 4);
    float pk[NE], pv[NE];
#pragma unroll
    for (int e = 0; e < NE; e++) { pk[e] = 0.f; pv[e] = 0.f; }
#pragma unroll
    for (int j = 0; j < 8; j++) {
        const int i = lane * 8 + j;
        const float* gk = kgw + (size_t)i * NE;
        const float* gv = vgw + (size_t)i * NE;
#pragma unroll
        for (int e = 0; e < NE; e++) { pk[e] += xr[j] * gk[e]; pv[e] += xr[j] * gv[e]; }
    }
#pragma unroll
    for (int off = 32; off > 0; off >>= 1)
#pragma unroll
        for (int e = 0; e < NE; e++) { pk[e] += __shfl_down(pk[e], off); pv[e] += __shfl_down(pv[e], off); }
    if (lane == 0) { topk_write(pk, kgb, Gk, t); topk_write(pv, vgb, Gv, t); }
}

// ---------------- out[t,n] = sum_e g[t,e]*b[e,n]  (bias pre-init for atomic GEMMs) ------
__global__ void gate_bias_init(const float* __restrict__ G, const float* __restrict__ b,
                               float* __restrict__ out)
{
    const int idx = blockIdx.x * 256 + threadIdx.x;
    const int t = idx >> 9, n = idx & 511;
    const float* g = G + (size_t)t * NE;
    float s = 0.f;
#pragma unroll
    for (int e = 0; e < NE; e++) s += g[e] * b[e * DM + n];
    out[idx] = s;
}

// ---------------- fused k+v MoE GEMM: 128x128 tile, BK=64, STATIC double-buffer ---------
// 2-phase pipeline with statically-named LDS buffers (As0/As1): gl16 into buf B while
// MFMA reads buf A -- distinct objects let alias analysis skip the vmcnt wait before
// ds_reads; the syncthreads drain lands after compute has covered load latency.
__global__ __launch_bounds__(256, 2)
void moe_gemm_kv(const bf16_t* __restrict__ X,
                 const bf16_t* __restrict__ Wk, const bf16_t* __restrict__ Wv,
                 const float* __restrict__ kb, const float* __restrict__ vb,
                 const float* __restrict__ Gk, const float* __restrict__ Gv,
                 bf16_t* __restrict__ kp, bf16_t* __restrict__ vpT)
{
    constexpr int BM = 128, BN = 128, BK = 64;
    __shared__ bf16_t As0[BM * BK];
    __shared__ bf16_t As1[BM * BK];
    __shared__ bf16_t Bs0[BN * BK];
    __shared__ bf16_t Bs1[BN * BK];
    __shared__ float Gs[BM][NE];
    __shared__ float BiasS[NE][BN];

    const int tid = threadIdx.x, lane = tid & 63, w = tid >> 6;
    const int wr = w >> 1, wc = w & 1;
    const int l15 = lane & 15, quad = lane >> 4;
    // XCD swizzle: flat = by*64+bx; new = (flat%8)*64 + flat/8 (bijective, 512 blocks)
    const int fl = blockIdx.y * 64 + blockIdx.x;
    const int nfl = ((fl & 7) << 6) | (fl >> 3);
    const int bx = nfl & 63, by = nfl >> 6;
    const int m0 = bx * BM;
    const int side = by >> 2;                    // 0:k 1:v
    const int n0 = (by & 3) * BN;
    const bf16_t* Wt = side ? Wv : Wk;
    const float* G = side ? Gv : Gk;
    const float* bias = side ? vb : kb;

    for (int i = tid; i < BM * NE; i += 256) {
        int r = i / NE, e = i - r * NE;
        Gs[r][e] = G[(size_t)(m0 + r) * NE + e];
    }
    for (int i = tid; i < NE * BN; i += 256) {
        int e = i / BN, j = i - e * BN;
        BiasS[e][j] = bias[(size_t)e * DM + n0 + j];
    }

    const int rsub = lane >> 3, pch = lane & 7, csw = pch ^ rsub;
    const bf16_t* aptr[4]; int soff[4];
#pragma unroll
    for (int j = 0; j < 4; j++) {
        const int rb = w * 32 + j * 8;
        aptr[j] = X + (size_t)(m0 + rb + rsub) * DM + csw * 8;
        soff[j] = rb * BK;
    }
    const bf16_t* wb0 = Wt + ((size_t)(n0 + w * 32 + rsub)) * DM + csw * 8;
    int amr[4], bnr[4];
#pragma unroll
    for (int f = 0; f < 4; f++) { amr[f] = wr * 64 + f * 16 + l15; bnr[f] = wc * 64 + f * 16 + l15; }

    // stage flat-iteration it into the given (statically-named) buffers
    auto stage = [&](bf16_t* Ad, bf16_t* Bd, int it) __attribute__((always_inline)) {
        const int e_ = it >> 3, kt_ = it & 7;
        const bf16_t* bb = wb0 + (size_t)e_ * (DM * DM) + kt_ * BK;
#pragma unroll
        for (int j = 0; j < 4; j++) gl16(aptr[j] + kt_ * BK, Ad + soff[j]);
#pragma unroll
        for (int j = 0; j < 4; j++) gl16(bb + (size_t)j * 8 * DM, Bd + soff[j]);
    };

    const f32x4 zv = {0.f, 0.f, 0.f, 0.f};
    f32x4 acc[4][4];
#pragma unroll
    for (int a = 0; a < 4; a++)
#pragma unroll
        for (int c = 0; c < 4; c++) acc[a][c] = zv;

    stage(As0, Bs0, 0);
    __syncthreads();                 // prologue loads landed; Gs/BiasS visible

    for (int e = 0; e < NE; e++) {
        f32x4 acc2[4][4];
#pragma unroll
        for (int a = 0; a < 4; a++)
#pragma unroll
            for (int c = 0; c < 4; c++) acc2[a][c] = zv;

#pragma unroll
        for (int kpair = 0; kpair < 4; kpair++) {
            const int it = e * 8 + kpair * 2;
            // phase A: stage (it+1)->buf1 while computing buf0(it)
            stage(As1, Bs1, it + 1);
#pragma unroll
            for (int kss = 0; kss < 2; kss++) {
                bf16x8 af[4], bfv[4];
#pragma unroll
                for (int f = 0; f < 4; f++) {
                    af[f]  = *(const bf16x8*)(As0 + amr[f] * BK + (((kss << 2) | quad) ^ (amr[f] & 7)) * 8);
                    bfv[f] = *(const bf16x8*)(Bs0 + bnr[f] * BK + (((kss << 2) | quad) ^ (bnr[f] & 7)) * 8);
                }
#pragma unroll
                for (int mf = 0; mf < 4; mf++)
#pragma unroll
                    for (int nf = 0; nf < 4; nf++)
                        acc2[mf][nf] = __builtin_amdgcn_mfma_f32_16x16x32_bf16(
                            af[mf], bfv[nf], acc2[mf][nf], 0, 0, 0);
            }
            __syncthreads();         // buf1 ready; everyone done reading buf0
            // phase B: stage (it+2)->buf0 while computing buf1(it+1)
            if (it + 2 < NE * 8) stage(As0, Bs0, it + 2);
#pragma unroll
            for (int kss = 0; kss < 2; kss++) {
                bf16x8 af[4], bfv[4];
#pragma unroll
                for (int f = 0; f < 4; f++) {
                    af[f]  = *(const bf16x8*)(As1 + amr[f] * BK + (((kss << 2) | quad) ^ (amr[f] & 7)) * 8);
                    bfv[f] = *(const bf16x8*)(Bs1 + bnr[f] * BK + (((kss << 2) | quad) ^ (bnr[f] & 7)) * 8);
                }
#pragma unroll
                for (int mf = 0; mf < 4; mf++)
#pragma unroll
                    for (int nf = 0; nf < 4; nf++)
                        acc2[mf][nf] = __builtin_amdgcn_mfma_f32_16x16x32_bf16(
                            af[mf], bfv[nf], acc2[mf][nf], 0, 0, 0);
            }
            __syncthreads();         // buf0(it+2) ready for next pair
        }
#pragma unroll
        for (int mf = 0; mf < 4; mf++)
#pragma unroll
            for (int r = 0; r < 4; r++) {
                const float g = Gs[wr * 64 + mf * 16 + quad * 4 + r][e];
#pragma unroll
                for (int nf = 0; nf < 4; nf++) acc[mf][nf][r] += g * acc2[mf][nf][r];
            }
    }

#pragma unroll
    for (int mf = 0; mf < 4; mf++) {
#pragma unroll
        for (int nf = 0; nf < 4; nf++) {
            const int n = wc * 64 + nf * 16 + l15;
            float vals[4];
#pragma unroll
            for (int r = 0; r < 4; r++) {
                const int m = wr * 64 + mf * 16 + quad * 4 + r;
                float v = acc[mf][nf][r];
#pragma unroll
                for (int e = 0; e < NE; e++) v += Gs[m][e] * BiasS[e][n];
                vals[r] = v;
            }
            if (side) {   // vpT: [b][dim 512][tok 4096], 4 consecutive tokens packed
                const int mg = m0 + wr * 64 + mf * 16 + quad * 4;
                const int b = mg >> 12, t = mg & 4095;
                bf16x4 pk;
                pk[0] = (bf16_t)vals[0]; pk[1] = (bf16_t)vals[1];
                pk[2] = (bf16_t)vals[2]; pk[3] = (bf16_t)vals[3];
                *(bf16x4*)(vpT + ((size_t)(b * DM) + n0 + n) * 4096 + t) = pk;
            } else {
#pragma unroll
                for (int r = 0; r < 4; r++) {
                    const int m = wr * 64 + mf * 16 + quad * 4 + r;
                    kp[(size_t)(m0 + m) * DM + n0 + n] = (bf16_t)vals[r];
                }
            }
        }
    }
}

// ---------------- expert-split MoE GEMM (small M): 2 experts/block, fp32 atomic out -----
// Bias handled by gate_bias_init. Grid (M/64, 512/64, 5). XCD chunk=80 swizzle.
__global__ __launch_bounds__(256, 4)
void moe_gemm_split(const bf16_t* __restrict__ X, const bf16_t* __restrict__ Wt,
                    const float* __restrict__ G, float* __restrict__ out)
{
    constexpr int BK = 64;
    __shared__ bf16_t As[64 * BK];
    __shared__ bf16_t Bs[64 * BK];
    __shared__ float Gs[64][2];
    const int tid = threadIdx.x, lane = tid & 63, w = tid >> 6;
    const int wr = w >> 1, wc = w & 1;
    const int l15 = lane & 15, quad = lane >> 4;
    // XCD swizzle: 640 blocks, chunk 80
    const int fl = blockIdx.z * 128 + blockIdx.y * 16 + blockIdx.x;
    const int nfl = (fl & 7) * 80 + (fl >> 3);
    const int bx = nfl & 15, by = (nfl >> 4) & 7, bz = nfl >> 7;
    const int m0 = bx * 64, n0 = by * 64, e0 = bz * 2;

    if (tid < 128) {
        int r = tid >> 1, e = tid & 1;
        Gs[r][e] = G[(size_t)(m0 + r) * NE + e0 + e];
    }

    const int rsub = lane >> 3, pch = lane & 7, csw = pch ^ rsub;
    const bf16_t* aptr[2]; bf16_t* alds[2]; bf16_t* blds[2];
#pragma unroll
    for (int j = 0; j < 2; j++) {
        const int rb = w * 16 + j * 8;
        aptr[j] = X + (size_t)(m0 + rb + rsub) * DM + csw * 8;
        alds[j] = (bf16_t*)As + rb * BK;
        blds[j] = (bf16_t*)Bs + rb * BK;
    }
    const int amr[2] = {wr * 32 + l15, wr * 32 + 16 + l15};
    const int bnr[2] = {wc * 32 + l15, wc * 32 + 16 + l15};

    const f32x4 zv = {0.f, 0.f, 0.f, 0.f};
    f32x4 acc[2][2];
#pragma unroll
    for (int a = 0; a < 2; a++)
#pragma unroll
        for (int c = 0; c < 2; c++) acc[a][c] = zv;

#pragma unroll
    for (int ee = 0; ee < 2; ee++) {
        const int e = e0 + ee;
        const bf16_t* bbase = Wt + ((size_t)e * DM + n0 + w * 16 + rsub) * DM + csw * 8;
        f32x4 acc2[2][2];
#pragma unroll
        for (int a = 0; a < 2; a++)
#pragma unroll
            for (int c = 0; c < 2; c++) acc2[a][c] = zv;
        for (int kt = 0; kt < 8; kt++) {
            __syncthreads();
#pragma unroll
            for (int j = 0; j < 2; j++) gl16(aptr[j] + kt * BK, alds[j]);
#pragma unroll
            for (int j = 0; j < 2; j++) gl16(bbase + (size_t)j * 8 * DM + kt * BK, blds[j]);
            __syncthreads();
#pragma unroll
            for (int kss = 0; kss < 2; kss++) {
                bf16x8 af[2], bfv[2];
#pragma unroll
                for (int f = 0; f < 2; f++) {
                    af[f]  = *(const bf16x8*)(As + amr[f] * BK + (((kss << 2) | quad) ^ (amr[f] & 7)) * 8);
                    bfv[f] = *(const bf16x8*)(Bs + bnr[f] * BK + (((kss << 2) | quad) ^ (bnr[f] & 7)) * 8);
                }
#pragma unroll
                for (int mf = 0; mf < 2; mf++)
#pragma unroll
                    for (int nf = 0; nf < 2; nf++)
                        acc2[mf][nf] = __builtin_amdgcn_mfma_f32_16x16x32_bf16(
                            af[mf], bfv[nf], acc2[mf][nf], 0, 0, 0);
            }
        }
#pragma unroll
        for (int mf = 0; mf < 2; mf++)
#pragma unroll
            for (int r = 0; r < 4; r++) {
                const float g = Gs[wr * 32 + mf * 16 + quad * 4 + r][ee];
#pragma unroll
                for (int nf = 0; nf < 2; nf++) acc[mf][nf][r] += g * acc2[mf][nf][r];
            }
    }
#pragma unroll
    for (int mf = 0; mf < 2; mf++)
#pragma unroll
        for (int nf = 0; nf < 2; nf++) {
            const int n = n0 + wc * 32 + nf * 16 + l15;
#pragma unroll
            for (int r = 0; r < 4; r++) {
                const int m = m0 + wr * 32 + mf * 16 + quad * 4 + r;
                atomicAdd(&out[(size_t)m * DM + n], acc[mf][nf][r]);
            }
        }
}

// ---------------- attention pass 1: online (m,l) stats per row, K-split 4 ----------------
// XCD chunk=64 swizzle: each XCD owns 2 complete bh groups (K ~1 MB L2-resident).
__global__ __launch_bounds__(256, 2)
void attn_pass1(const float* __restrict__ qp, const bf16_t* __restrict__ kp,
                float* __restrict__ mws, float* __restrict__ lws)
{
    __shared__ bf16_t Qs[64][72];
    __shared__ bf16_t Ks[64 * 64];
    const int fl = (blockIdx.z << 5) | (blockIdx.y << 2) | blockIdx.x;
    const int nfl = ((fl & 7) << 6) | (fl >> 3);
    const int ksp = nfl & 3, qt = (nfl >> 2) & 7, bh = nfl >> 5;
    const int b = bh >> 3, h = bh & 7, q0 = qt * 64;
    const int tid = threadIdx.x, lane = tid & 63, w = tid >> 6;
    const int l15 = lane & 15, quad = lane >> 4;

    {   // stage Q * SCALE -> bf16 (qp is fp32)
        const int row = tid >> 2, cg = (tid & 3) * 16;
        const float* qs = qp + ((size_t)(b * 512 + q0 + row)) * DM + h * 64 + cg;
        float4 f[4];
#pragma unroll
        for (int j = 0; j < 4; j++) f[j] = *(const float4*)(qs + j * 4);
        bf16x8 o0, o1;
        o0[0]=(bf16_t)(f[0].x*SCALE_F); o0[1]=(bf16_t)(f[0].y*SCALE_F); o0[2]=(bf16_t)(f[0].z*SCALE_F); o0[3]=(bf16_t)(f[0].w*SCALE_F);
        o0[4]=(bf16_t)(f[1].x*SCALE_F); o0[5]=(bf16_t)(f[1].y*SCALE_F); o0[6]=(bf16_t)(f[1].z*SCALE_F); o0[7]=(bf16_t)(f[1].w*SCALE_F);
        o1[0]=(bf16_t)(f[2].x*SCALE_F); o1[1]=(bf16_t)(f[2].y*SCALE_F); o1[2]=(bf16_t)(f[2].z*SCALE_F); o1[3]=(bf16_t)(f[2].w*SCALE_F);
        o1[4]=(bf16_t)(f[3].x*SCALE_F); o1[5]=(bf16_t)(f[3].y*SCALE_F); o1[6]=(bf16_t)(f[3].z*SCALE_F); o1[7]=(bf16_t)(f[3].w*SCALE_F);
        *(bf16x8*)&Qs[row][cg] = o0;
        *(bf16x8*)&Qs[row][cg + 8] = o1;
    }
    const int rsub = lane >> 3, pch = lane & 7, csw = pch ^ rsub;
    const bf16_t* kptr[2]; bf16_t* klds[2];
#pragma unroll
    for (int j = 0; j < 2; j++) {
        const int rb = w * 16 + j * 8;
        kptr[j] = kp + ((size_t)(b * 4096 + rb + rsub)) * DM + h * 64 + csw * 8;
        klds[j] = (bf16_t*)Ks + rb * 64;
    }
    float mrun[4], lrun[4];
#pragma unroll
    for (int r = 0; r < 4; r++) { mrun[r] = -3.0e38f; lrun[r] = 0.f; }

    for (int kt = 0; kt < 16; kt++) {
        const size_t koff = (size_t)(ksp * 16 + kt) * 64 * DM;
        __syncthreads();
        gl16(kptr[0] + koff, klds[0]);
        gl16(kptr[1] + koff, klds[1]);
        __syncthreads();
        const f32x4 zv = {0.f, 0.f, 0.f, 0.f};
        f32x4 sacc[4] = {zv, zv, zv, zv};
#pragma unroll
        for (int kss = 0; kss < 2; kss++) {
            bf16x8 af = *(const bf16x8*)&Qs[w * 16 + l15][kss * 32 + quad * 8];
#pragma unroll
            for (int nf = 0; nf < 4; nf++) {
                const int br = nf * 16 + l15;
                bf16x8 bfv = *(const bf16x8*)(Ks + br * 64 + (((kss << 2) | quad) ^ (br & 7)) * 8);
                sacc[nf] = __builtin_amdgcn_mfma_f32_16x16x32_bf16(af, bfv, sacc[nf], 0, 0, 0);
            }
        }
#pragma unroll
        for (int r = 0; r < 4; r++) {
            float tm = fmaxf(fmaxf(sacc[0][r], sacc[1][r]), fmaxf(sacc[2][r], sacc[3][r]));
#pragma unroll
            for (int off = 1; off < 16; off <<= 1) tm = fmaxf(tm, __shfl_xor(tm, off));
            const float mn = fmaxf(mrun[r], tm);
            float s = __expf(sacc[0][r] - mn) + __expf(sacc[1][r] - mn) +
                      __expf(sacc[2][r] - mn) + __expf(sacc[3][r] - mn);
#pragma unroll
            for (int off = 1; off < 16; off <<= 1) s += __shfl_xor(s, off);
            lrun[r] = lrun[r] * __expf(mrun[r] - mn) + s;
            mrun[r] = mn;
        }
    }
    if (l15 == 0) {
#pragma unroll
        for (int r = 0; r < 4; r++) {
            const int row = q0 + w * 16 + quad * 4 + r;
            mws[((size_t)ksp * 16 + bh) * 512 + row] = mrun[r];
            lws[((size_t)ksp * 16 + bh) * 512 + row] = lrun[r];
        }
    }
}

// ---------------- attention pass 2: recompute S, write P to d_out, fused PV -------------
// XCD chunk=64 swizzle (same as pass 1): K+V ~2 MB per XCD, qt-blocks co-located.
__global__ __launch_bounds__(256, 2)
void attn_pass2(const float* __restrict__ qp, const bf16_t* __restrict__ kp,
                const bf16_t* __restrict__ vpT, const float* __restrict__ mws,
                const float* __restrict__ lws, float* __restrict__ attn,
                float* __restrict__ xout)
{
    __shared__ bf16_t Qs[64][72];
    __shared__ bf16_t Ks[64 * 64];
    __shared__ bf16_t Vs[64 * 64];
    __shared__ bf16_t Ps[64][72];
    const int fl = (blockIdx.z << 5) | (blockIdx.y << 2) | blockIdx.x;
    const int nfl = ((fl & 7) << 6) | (fl >> 3);
    const int ksp = nfl & 3, qt = (nfl >> 2) & 7, bh = nfl >> 5;
    const int b = bh >> 3, h = bh & 7, q0 = qt * 64;
    const int tid = threadIdx.x, lane = tid & 63, w = tid >> 6;
    const int l15 = lane & 15, quad = lane >> 4;

    {   // stage Q * SCALE
        const int row = tid >> 2, cg = (tid & 3) * 16;
        const float* qs = qp + ((size_t)(b * 512 + q0 + row)) * DM + h * 64 + cg;
        float4 f[4];
#pragma unroll
        for (int j = 0; j < 4; j++) f[j] = *(const float4*)(qs + j * 4);
        bf16x8 o0, o1;
        o0[0]=(bf16_t)(f[0].x*SCALE_F); o0[1]=(bf16_t)(f[0].y*SCALE_F); o0[2]=(bf16_t)(f[0].z*SCALE_F); o0[3]=(bf16_t)(f[0].w*SCALE_F);
        o0[4]=(bf16_t)(f[1].x*SCALE_F); o0[5]=(bf16_t)(f[1].y*SCALE_F); o0[6]=(bf16_t)(f[1].z*SCALE_F); o0[7]=(bf16_t)(f[1].w*SCALE_F);
        o1[0]=(bf16_t)(f[2].x*SCALE_F); o1[1]=(bf16_t)(f[2].y*SCALE_F); o1[2]=(bf16_t)(f[2].z*SCALE_F); o1[3]=(bf16_t)(f[2].w*SCALE_F);
        o1[4]=(bf16_t)(f[3].x*SCALE_F); o1[5]=(bf16_t)(f[3].y*SCALE_F); o1[6]=(bf16_t)(f[3].z*SCALE_F); o1[7]=(bf16_t)(f[3].w*SCALE_F);
        *(bf16x8*)&Qs[row][cg] = o0;
        *(bf16x8*)&Qs[row][cg + 8] = o1;
    }
    // combined stats for my 4 rows
    float mrow[4], linv[4];
#pragma unroll
    for (int r = 0; r < 4; r++) {
        const int row = q0 + w * 16 + quad * 4 + r;
        float mv[4], lv[4], mm = -3.0e38f;
#pragma unroll
        for (int p = 0; p < 4; p++) {
            mv[p] = mws[((size_t)p * 16 + bh) * 512 + row];
            lv[p] = lws[((size_t)p * 16 + bh) * 512 + row];
            mm = fmaxf(mm, mv[p]);
        }
        float ll = 0.f;
#pragma unroll
        for (int p = 0; p < 4; p++) ll += lv[p] * __expf(mv[p] - mm);
        mrow[r] = mm; linv[r] = 1.f / ll;
    }
    const int rsub = lane >> 3, pch = lane & 7, csw = pch ^ rsub;
    const bf16_t* kptr[2]; const bf16_t* vptr[2]; bf16_t* klds[2]; bf16_t* vlds[2];
#pragma unroll
    for (int j = 0; j < 2; j++) {
        const int rb = w * 16 + j * 8;
        kptr[j] = kp + ((size_t)(b * 4096 + rb + rsub)) * DM + h * 64 + csw * 8;
        vptr[j] = vpT + ((size_t)(b * DM + h * 64 + rb + rsub)) * 4096 + csw * 8;
        klds[j] = (bf16_t*)Ks + rb * 64;
        vlds[j] = (bf16_t*)Vs + rb * 64;
    }
    const f32x4 zv = {0.f, 0.f, 0.f, 0.f};
    f32x4 oacc[4] = {zv, zv, zv, zv};
    float* ap = attn + ((size_t)bh * 512) * 4096;

    for (int kt = 0; kt < 16; kt++) {
        const int kg = (ksp * 16 + kt) * 64;
        __syncthreads();
        gl16(kptr[0] + (size_t)kg * DM, klds[0]);
        gl16(kptr[1] + (size_t)kg * DM, klds[1]);
        gl16(vptr[0] + kg, vlds[0]);
        gl16(vptr[1] + kg, vlds[1]);
        __syncthreads();
        f32x4 sacc[4] = {zv, zv, zv, zv};
#pragma unroll
        for (int kss = 0; kss < 2; kss++) {
            bf16x8 af = *(const bf16x8*)&Qs[w * 16 + l15][kss * 32 + quad * 8];
#pragma unroll
            for (int nf = 0; nf < 4; nf++) {
                const int br = nf * 16 + l15;
                bf16x8 bfv = *(const bf16x8*)(Ks + br * 64 + (((kss << 2) | quad) ^ (br & 7)) * 8);
                sacc[nf] = __builtin_amdgcn_mfma_f32_16x16x32_bf16(af, bfv, sacc[nf], 0, 0, 0);
            }
        }
#pragma unroll
        for (int nf = 0; nf < 4; nf++)
#pragma unroll
            for (int r = 0; r < 4; r++) {
                const float p = __expf(sacc[nf][r] - mrow[r]) * linv[r];
                ap[((size_t)(q0 + w * 16 + quad * 4 + r)) * 4096 + kg + nf * 16 + l15] = p;
                Ps[w * 16 + quad * 4 + r][nf * 16 + l15] = (bf16_t)p;
            }
        __syncthreads();
#pragma unroll
        for (int kss = 0; kss < 2; kss++) {
            bf16x8 paf = *(const bf16x8*)&Ps[w * 16 + l15][kss * 32 + quad * 8];
#pragma unroll
            for (int nf = 0; nf < 4; nf++) {
                const int br = nf * 16 + l15;
                bf16x8 vb = *(const bf16x8*)(Vs + br * 64 + (((kss << 2) | quad) ^ (br & 7)) * 8);
                oacc[nf] = __builtin_amdgcn_mfma_f32_16x16x32_bf16(paf, vb, oacc[nf], 0, 0, 0);
            }
        }
    }
#pragma unroll
    for (int nf = 0; nf < 4; nf++) {
        const int n = h * 64 + nf * 16 + l15;
#pragma unroll
        for (int r = 0; r < 4; r++) {
            const int m = b * 512 + q0 + w * 16 + quad * 4 + r;
            atomicAdd(&xout[(size_t)m * DM + n], oacc[nf][r]);
        }
    }
}

// ---------------- host ----------------
extern "C" void kernel_launch(void* const* d_in, const int* in_sizes, int n_in,
                              void* d_out, int out_size, void* d_ws, size_t ws_size,
                              hipStream_t stream)
{
    (void)in_sizes; (void)n_in; (void)out_size; (void)ws_size;
    const float* q    = (const float*)d_in[0];
    const float* kv   = (const float*)d_in[1];
    const float* q_gw = (const float*)d_in[2];
    const float* q_gb = (const float*)d_in[3];
    const float* q_w  = (const float*)d_in[4];
    const float* q_b  = (const float*)d_in[5];
    const float* k_gw = (const float*)d_in[6];
    const float* k_gb = (const float*)d_in[7];
    const float* k_w  = (const float*)d_in[8];
    const float* k_b  = (const float*)d_in[9];
    const float* v_gw = (const float*)d_in[10];
    const float* v_gb = (const float*)d_in[11];
    const float* v_w  = (const float*)d_in[12];
    const float* v_b  = (const float*)d_in[13];
    const float* o_gw = (const float*)d_in[14];
    const float* o_gb = (const float*)d_in[15];
    const float* o_w  = (const float*)d_in[16];
    const float* o_b  = (const float*)d_in[17];

    float* out0 = (float*)d_out;
    float* attn = out0 + (size_t)1024 * 512;

    char* ws = (char*)d_ws;
    size_t off = 0;
    auto alloc = [&](size_t bytes) {
        void* p = ws + off;
        off += (bytes + 255) & ~(size_t)255;
        return p;
    };
    bf16_t* Xq    = (bf16_t*)alloc((size_t)1024 * 512 * 2);
    bf16_t* Xkv   = (bf16_t*)alloc((size_t)8192 * 512 * 2);
    bf16_t* Wall  = (bf16_t*)alloc((size_t)4 * NE * 512 * 512 * 2);
    bf16_t* Wq_t  = Wall;
    bf16_t* Wk_t  = Wall + (size_t)1 * NE * 512 * 512;
    bf16_t* Wv_t  = Wall + (size_t)2 * NE * 512 * 512;
    bf16_t* Wo_t  = Wall + (size_t)3 * NE * 512 * 512;
    float*  qpf   = (float*)alloc((size_t)1024 * 512 * 4);   // q-proj fp32 (atomic)
    bf16_t* kp    = (bf16_t*)alloc((size_t)8192 * 512 * 2);
    bf16_t* vpT   = (bf16_t*)alloc((size_t)8192 * 512 * 2);
    float*  xatt  = (float*)alloc((size_t)1024 * 512 * 4);
    bf16_t* xbf   = (bf16_t*)alloc((size_t)1024 * 512 * 2);
    float*  Gq    = (float*)alloc((size_t)1024 * NE * 4);
    float*  Gk    = (float*)alloc((size_t)8192 * NE * 4);
    float*  Gv    = (float*)alloc((size_t)8192 * NE * 4);
    float*  Go    = (float*)alloc((size_t)1024 * NE * 4);
    float*  mws   = (float*)alloc((size_t)4 * 16 * 512 * 4);
    float*  lws   = (float*)alloc((size_t)4 * 16 * 512 * 4);

    cast_bf16_kernel<<<256, 256, 0, stream>>>(q, Xq, 1024 * 512);
    cast_bf16_kernel<<<2048, 256, 0, stream>>>(kv, Xkv, 8192 * 512);
    wtrans4_kernel<<<dim3(16, 16, 4 * NE), 256, 0, stream>>>(q_w, k_w, v_w, o_w, Wall);
    moe_gates<<<1024, 64, 0, stream>>>(q, q_gw, q_gb, Gq);
    moe_gates_kv<<<2048, 256, 0, stream>>>(kv, k_gw, k_gb, v_gw, v_gb, Gk, Gv);

    gate_bias_init<<<2048, 256, 0, stream>>>(Gq, q_b, qpf);
    moe_gemm_split<<<dim3(16, 8, 5), 256, 0, stream>>>(Xq, Wq_t, Gq, qpf);
    moe_gemm_kv<<<dim3(64, 8), 256, 0, stream>>>(Xkv, Wk_t, Wv_t, k_b, v_b, Gk, Gv, kp, vpT);

    attn_pass1<<<dim3(4, 8, 16), 256, 0, stream>>>(qpf, kp, mws, lws);
    hipMemsetAsync(xatt, 0, (size_t)1024 * 512 * 4, stream);
    attn_pass2<<<dim3(4, 8, 16), 256, 0, stream>>>(qpf, kp, vpT, mws, lws, attn, xatt);

    moe_gates<<<1024, 64, 0, stream>>>(xatt, o_gw, o_gb, Go);
    cast_bf16_kernel<<<256, 256, 0, stream>>>(xatt, xbf, 1024 * 512);
    gate_bias_init<<<2048, 256, 0, stream>>>(Go, o_b, out0);
    moe_gemm_split<<<dim3(16, 8, 5), 256, 0, stream>>>(xbf, Wo_t, Go, out0);
}

// Round 5
// 460.617 us; speedup vs baseline: 1.1073x; 1.1073x over previous
//
#include <hip/hip_runtime.h>
#include <hip/hip_bf16.h>

typedef __bf16 bf16_t;
typedef __bf16 bf16x8 __attribute__((ext_vector_type(8)));
typedef __bf16 bf16x4 __attribute__((ext_vector_type(4)));
typedef float f32x4 __attribute__((ext_vector_type(4)));

#define NE 10
#define DM 512
#define SCALE_F 0.125f

// async global->LDS, 16B per lane. LDS dst is wave-uniform base + lane*16.
__device__ __forceinline__ void gl16(const void* g, void* l) {
    __builtin_amdgcn_global_load_lds(
        (const __attribute__((address_space(1))) unsigned int*)g,
        (__attribute__((address_space(3))) unsigned int*)l, 16, 0, 0);
}

// ---------------- cast fp32 -> bf16 (8 elems/thread) ----------------
__global__ void cast_bf16_kernel(const float* __restrict__ in, bf16_t* __restrict__ out, int n)
{
    const int i = (blockIdx.x * 256 + threadIdx.x) * 8;
    if (i >= n) return;
    float4 a = *(const float4*)(in + i);
    float4 b = *(const float4*)(in + i + 4);
    bf16x8 o;
    o[0] = (bf16_t)a.x; o[1] = (bf16_t)a.y; o[2] = (bf16_t)a.z; o[3] = (bf16_t)a.w;
    o[4] = (bf16_t)b.x; o[5] = (bf16_t)b.y; o[6] = (bf16_t)b.z; o[7] = (bf16_t)b.w;
    *(bf16x8*)(out + i) = o;
}

// ---------------- 4x W[e][k][n] fp32 -> Wt[which][e][n][k] bf16 (fused) ----------------
__global__ void wtrans4_kernel(const float* __restrict__ W0, const float* __restrict__ W1,
                               const float* __restrict__ W2, const float* __restrict__ W3,
                               bf16_t* __restrict__ Wt)
{
    __shared__ float tile[32][33];
    const int z = blockIdx.z, which = z / NE, e = z - which * NE;
    const float* W = which == 0 ? W0 : which == 1 ? W1 : which == 2 ? W2 : W3;
    const int n0 = blockIdx.x * 32, k0 = blockIdx.y * 32;
    const int tx = threadIdx.x & 31, ty = threadIdx.x >> 5; // ty 0..7
    const float* Wp = W + ((size_t)e * DM + k0) * DM + n0;
#pragma unroll
    for (int r = 0; r < 32; r += 8) tile[ty + r][tx] = Wp[(size_t)(ty + r) * DM + tx];
    __syncthreads();
    bf16_t* Op = Wt + (((size_t)which * NE + e) * DM + n0) * DM + k0;
#pragma unroll
    for (int r = 0; r < 32; r += 8) Op[(size_t)(ty + r) * DM + tx] = (bf16_t)tile[tx][ty + r];
}

// ---------------- top-k gate selection + renorm (fp32, matches lax.top_k ties) ----------
__device__ __forceinline__ void topk_write(const float* p, const float* __restrict__ gb,
                                           float* __restrict__ G, int t)
{
    float l[NE], ex[NE];
    float mx = -3.4e38f;
#pragma unroll
    for (int e = 0; e < NE; e++) { l[e] = p[e] + gb[e]; mx = fmaxf(mx, l[e]); }
#pragma unroll
    for (int e = 0; e < NE; e++) ex[e] = __expf(l[e] - mx);
    bool sel[NE];
#pragma unroll
    for (int e = 0; e < NE; e++) sel[e] = false;
    float ssel = 0.f;
    for (int j = 0; j < 5; j++) {
        int bi = 0; float bv = -3.4e38f;
        for (int e = 0; e < NE; e++)
            if (!sel[e] && l[e] > bv) { bv = l[e]; bi = e; }
        sel[bi] = true; ssel += ex[bi];
    }
    const float inv = 1.f / ssel;
    for (int e = 0; e < NE; e++) G[(size_t)t * NE + e] = sel[e] ? ex[e] * inv : 0.f;
}

// one 64-thread block per token
__global__ void moe_gates(const float* __restrict__ X, const float* __restrict__ gw,
                          const float* __restrict__ gb, float* __restrict__ G)
{
    const int t = blockIdx.x;
    const int lane = threadIdx.x;
    const float* x = X + (size_t)t * DM;
    float p[NE];
#pragma unroll
    for (int e = 0; e < NE; e++) p[e] = 0.f;
    for (int i = lane; i < DM; i += 64) {
        const float xv = x[i];
        const float* g = gw + (size_t)i * NE;
#pragma unroll
        for (int e = 0; e < NE; e++) p[e] += xv * g[e];
    }
#pragma unroll
    for (int off = 32; off > 0; off >>= 1)
#pragma unroll
        for (int e = 0; e < NE; e++) p[e] += __shfl_down(p[e], off);
    if (lane == 0) topk_write(p, gb, G, t);
}

// fused k+v gates: 4 waves/block, one token per wave, X read once
__global__ void moe_gates_kv(const float* __restrict__ X,
                             const float* __restrict__ kgw, const float* __restrict__ kgb,
                             const float* __restrict__ vgw, const float* __restrict__ vgb,
                             float* __restrict__ Gk, float* __restrict__ Gv)
{
    const int t = blockIdx.x * 4 + (threadIdx.x >> 6);
    const int lane = threadIdx.x & 63;
    const float* x = X + (size_t)t * DM;
    float xr[8];
    *(float4*)&xr[0] = *(const float4*)(x + lane * 8);
    *(float4*)&xr[4] = *(const float4*)(x + lane * 8 + 4);
    float pk[NE], pv[NE];
#pragma unroll
    for (int e = 0; e < NE; e++) { pk[e] = 0.f; pv[e] = 0.f; }
#pragma unroll
    for (int j = 0; j < 8; j++) {
        const int i = lane * 8 + j;
        const float* gk = kgw + (size_t)i * NE;
        const float* gv = vgw + (size_t)i * NE;
#pragma unroll
        for (int e = 0; e < NE; e++) { pk[e] += xr[j] * gk[e]; pv[e] += xr[j] * gv[e]; }
    }
#pragma unroll
    for (int off = 32; off > 0; off >>= 1)
#pragma unroll
        for (int e = 0; e < NE; e++) { pk[e] += __shfl_down(pk[e], off); pv[e] += __shfl_down(pv[e], off); }
    if (lane == 0) { topk_write(pk, kgb, Gk, t); topk_write(pv, vgb, Gv, t); }
}

// ---------------- out[t,n] = sum_e g[t,e]*b[e,n]  (bias pre-init for atomic GEMMs) ------
__global__ void gate_bias_init(const float* __restrict__ G, const float* __restrict__ b,
                               float* __restrict__ out)
{
    const int idx = blockIdx.x * 256 + threadIdx.x;
    const int t = idx >> 9, n = idx & 511;
    const float* g = G + (size_t)t * NE;
    float s = 0.f;
#pragma unroll
    for (int e = 0; e < NE; e++) s += g[e] * b[e * DM + n];
    out[idx] = s;
}

// ---------------- fused k+v MoE GEMM: 128x128 tile, BK=64, async swizzled staging -------
// R2-verified plateau version: single-buffer 2-barrier loop (pipelining attempts R1/R3/R4
// all regressed: dbuf doubles L2 footprint -> X re-stream; no overlap materializes).
__global__ __launch_bounds__(256, 2)
void moe_gemm_kv(const bf16_t* __restrict__ X,
                 const bf16_t* __restrict__ Wk, const bf16_t* __restrict__ Wv,
                 const float* __restrict__ kb, const float* __restrict__ vb,
                 const float* __restrict__ Gk, const float* __restrict__ Gv,
                 bf16_t* __restrict__ kp, bf16_t* __restrict__ vpT)
{
    constexpr int BM = 128, BN = 128, BK = 64;
    __shared__ bf16_t As[BM * BK];
    __shared__ bf16_t Bs[BN * BK];
    __shared__ float Gs[BM][NE];
    __shared__ float BiasS[NE][BN];

    const int tid = threadIdx.x, lane = tid & 63, w = tid >> 6;
    const int wr = w >> 1, wc = w & 1;
    const int l15 = lane & 15, quad = lane >> 4;
    // XCD swizzle: flat = by*64+bx; new = (flat%8)*64 + flat/8 (bijective, 512 blocks)
    const int fl = blockIdx.y * 64 + blockIdx.x;
    const int nfl = ((fl & 7) << 6) | (fl >> 3);
    const int bx = nfl & 63, by = nfl >> 6;
    const int m0 = bx * BM;
    const int side = by >> 2;                    // 0:k 1:v
    const int n0 = (by & 3) * BN;
    const bf16_t* Wt = side ? Wv : Wk;
    const float* G = side ? Gv : Gk;
    const float* bias = side ? vb : kb;

    for (int i = tid; i < BM * NE; i += 256) {
        int r = i / NE, e = i - r * NE;
        Gs[r][e] = G[(size_t)(m0 + r) * NE + e];
    }
    for (int i = tid; i < NE * BN; i += 256) {
        int e = i / BN, j = i - e * BN;
        BiasS[e][j] = bias[(size_t)e * DM + n0 + j];
    }

    const int rsub = lane >> 3, pch = lane & 7, csw = pch ^ rsub;
    const bf16_t* aptr[4]; bf16_t* alds[4]; bf16_t* blds[4];
#pragma unroll
    for (int j = 0; j < 4; j++) {
        const int rb = w * 32 + j * 8;
        aptr[j] = X + (size_t)(m0 + rb + rsub) * DM + csw * 8;
        alds[j] = (bf16_t*)As + rb * BK;
        blds[j] = (bf16_t*)Bs + rb * BK;
    }
    int amr[4], bnr[4];
#pragma unroll
    for (int f = 0; f < 4; f++) { amr[f] = wr * 64 + f * 16 + l15; bnr[f] = wc * 64 + f * 16 + l15; }

    const f32x4 zv = {0.f, 0.f, 0.f, 0.f};
    f32x4 acc[4][4];
#pragma unroll
    for (int a = 0; a < 4; a++)
#pragma unroll
        for (int c = 0; c < 4; c++) acc[a][c] = zv;

    for (int e = 0; e < NE; e++) {
        const bf16_t* bbase = Wt + ((size_t)e * DM + n0 + w * 32 + rsub) * DM + csw * 8;
        f32x4 acc2[4][4];
#pragma unroll
        for (int a = 0; a < 4; a++)
#pragma unroll
            for (int c = 0; c < 4; c++) acc2[a][c] = zv;

        for (int kt = 0; kt < 8; kt++) {
            __syncthreads();
#pragma unroll
            for (int j = 0; j < 4; j++) gl16(aptr[j] + kt * BK, alds[j]);
#pragma unroll
            for (int j = 0; j < 4; j++) gl16(bbase + (size_t)j * 8 * DM + kt * BK, blds[j]);
            __syncthreads();
#pragma unroll
            for (int kss = 0; kss < 2; kss++) {
                bf16x8 af[4], bfv[4];
#pragma unroll
                for (int f = 0; f < 4; f++) {
                    af[f]  = *(const bf16x8*)(As + amr[f] * BK + (((kss << 2) | quad) ^ (amr[f] & 7)) * 8);
                    bfv[f] = *(const bf16x8*)(Bs + bnr[f] * BK + (((kss << 2) | quad) ^ (bnr[f] & 7)) * 8);
                }
#pragma unroll
                for (int mf = 0; mf < 4; mf++)
#pragma unroll
                    for (int nf = 0; nf < 4; nf++)
                        acc2[mf][nf] = __builtin_amdgcn_mfma_f32_16x16x32_bf16(
                            af[mf], bfv[nf], acc2[mf][nf], 0, 0, 0);
            }
        }
#pragma unroll
        for (int mf = 0; mf < 4; mf++)
#pragma unroll
            for (int r = 0; r < 4; r++) {
                const float g = Gs[wr * 64 + mf * 16 + quad * 4 + r][e];
#pragma unroll
                for (int nf = 0; nf < 4; nf++) acc[mf][nf][r] += g * acc2[mf][nf][r];
            }
    }

#pragma unroll
    for (int mf = 0; mf < 4; mf++) {
#pragma unroll
        for (int nf = 0; nf < 4; nf++) {
            const int n = wc * 64 + nf * 16 + l15;
            float vals[4];
#pragma unroll
            for (int r = 0; r < 4; r++) {
                const int m = wr * 64 + mf * 16 + quad * 4 + r;
                float v = acc[mf][nf][r];
#pragma unroll
                for (int e = 0; e < NE; e++) v += Gs[m][e] * BiasS[e][n];
                vals[r] = v;
            }
            if (side) {   // vpT: [b][dim 512][tok 4096], 4 consecutive tokens packed
                const int mg = m0 + wr * 64 + mf * 16 + quad * 4;
                const int b = mg >> 12, t = mg & 4095;
                bf16x4 pk;
                pk[0] = (bf16_t)vals[0]; pk[1] = (bf16_t)vals[1];
                pk[2] = (bf16_t)vals[2]; pk[3] = (bf16_t)vals[3];
                *(bf16x4*)(vpT + ((size_t)(b * DM) + n0 + n) * 4096 + t) = pk;
            } else {
#pragma unroll
                for (int r = 0; r < 4; r++) {
                    const int m = wr * 64 + mf * 16 + quad * 4 + r;
                    kp[(size_t)(m0 + m) * DM + n0 + n] = (bf16_t)vals[r];
                }
            }
        }
    }
}

// ---------------- expert-split MoE GEMM (small M): 2 experts/block, fp32 atomic out -----
// Bias handled by gate_bias_init. Grid (M/64, 512/64, 5). XCD chunk=80 swizzle.
__global__ __launch_bounds__(256, 4)
void moe_gemm_split(const bf16_t* __restrict__ X, const bf16_t* __restrict__ Wt,
                    const float* __restrict__ G, float* __restrict__ out)
{
    constexpr int BK = 64;
    __shared__ bf16_t As[64 * BK];
    __shared__ bf16_t Bs[64 * BK];
    __shared__ float Gs[64][2];
    const int tid = threadIdx.x, lane = tid & 63, w = tid >> 6;
    const int wr = w >> 1, wc = w & 1;
    const int l15 = lane & 15, quad = lane >> 4;
    // XCD swizzle: 640 blocks, chunk 80
    const int fl = blockIdx.z * 128 + blockIdx.y * 16 + blockIdx.x;
    const int nfl = (fl & 7) * 80 + (fl >> 3);
    const int bx = nfl & 15, by = (nfl >> 4) & 7, bz = nfl >> 7;
    const int m0 = bx * 64, n0 = by * 64, e0 = bz * 2;

    if (tid < 128) {
        int r = tid >> 1, e = tid & 1;
        Gs[r][e] = G[(size_t)(m0 + r) * NE + e0 + e];
    }

    const int rsub = lane >> 3, pch = lane & 7, csw = pch ^ rsub;
    const bf16_t* aptr[2]; bf16_t* alds[2]; bf16_t* blds[2];
#pragma unroll
    for (int j = 0; j < 2; j++) {
        const int rb = w * 16 + j * 8;
        aptr[j] = X + (size_t)(m0 + rb + rsub) * DM + csw * 8;
        alds[j] = (bf16_t*)As + rb * BK;
        blds[j] = (bf16_t*)Bs + rb * BK;
    }
    const int amr[2] = {wr * 32 + l15, wr * 32 + 16 + l15};
    const int bnr[2] = {wc * 32 + l15, wc * 32 + 16 + l15};

    const f32x4 zv = {0.f, 0.f, 0.f, 0.f};
    f32x4 acc[2][2];
#pragma unroll
    for (int a = 0; a < 2; a++)
#pragma unroll
        for (int c = 0; c < 2; c++) acc[a][c] = zv;

#pragma unroll
    for (int ee = 0; ee < 2; ee++) {
        const int e = e0 + ee;
        const bf16_t* bbase = Wt + ((size_t)e * DM + n0 + w * 16 + rsub) * DM + csw * 8;
        f32x4 acc2[2][2];
#pragma unroll
        for (int a = 0; a < 2; a++)
#pragma unroll
            for (int c = 0; c < 2; c++) acc2[a][c] = zv;
        for (int kt = 0; kt < 8; kt++) {
            __syncthreads();
#pragma unroll
            for (int j = 0; j < 2; j++) gl16(aptr[j] + kt * BK, alds[j]);
#pragma unroll
            for (int j = 0; j < 2; j++) gl16(bbase + (size_t)j * 8 * DM + kt * BK, blds[j]);
            __syncthreads();
#pragma unroll
            for (int kss = 0; kss < 2; kss++) {
                bf16x8 af[2], bfv[2];
#pragma unroll
                for (int f = 0; f < 2; f++) {
                    af[f]  = *(const bf16x8*)(As + amr[f] * BK + (((kss << 2) | quad) ^ (amr[f] & 7)) * 8);
                    bfv[f] = *(const bf16x8*)(Bs + bnr[f] * BK + (((kss << 2) | quad) ^ (bnr[f] & 7)) * 8);
                }
#pragma unroll
                for (int mf = 0; mf < 2; mf++)
#pragma unroll
                    for (int nf = 0; nf < 2; nf++)
                        acc2[mf][nf] = __builtin_amdgcn_mfma_f32_16x16x32_bf16(
                            af[mf], bfv[nf], acc2[mf][nf], 0, 0, 0);
            }
        }
#pragma unroll
        for (int mf = 0; mf < 2; mf++)
#pragma unroll
            for (int r = 0; r < 4; r++) {
                const float g = Gs[wr * 32 + mf * 16 + quad * 4 + r][ee];
#pragma unroll
                for (int nf = 0; nf < 2; nf++) acc[mf][nf][r] += g * acc2[mf][nf][r];
            }
    }
#pragma unroll
    for (int mf = 0; mf < 2; mf++)
#pragma unroll
        for (int nf = 0; nf < 2; nf++) {
            const int n = n0 + wc * 32 + nf * 16 + l15;
#pragma unroll
            for (int r = 0; r < 4; r++) {
                const int m = m0 + wr * 32 + mf * 16 + quad * 4 + r;
                atomicAdd(&out[(size_t)m * DM + n], acc[mf][nf][r]);
            }
        }
}

// ---------------- attention pass 1: online (m,l) stats per row, K-split 4 ----------------
// KVBLK=128: 4 gl16 + 16 MFMA per barrier pair (half the drains of the 64-row version).
__global__ __launch_bounds__(256, 2)
void attn_pass1(const float* __restrict__ qp, const bf16_t* __restrict__ kp,
                float* __restrict__ mws, float* __restrict__ lws)
{
    __shared__ bf16_t Qs[64][72];
    __shared__ bf16_t Ks[128 * 64];
    const int fl = (blockIdx.z << 5) | (blockIdx.y << 2) | blockIdx.x;
    const int nfl = ((fl & 7) << 6) | (fl >> 3);
    const int ksp = nfl & 3, qt = (nfl >> 2) & 7, bh = nfl >> 5;
    const int b = bh >> 3, h = bh & 7, q0 = qt * 64;
    const int tid = threadIdx.x, lane = tid & 63, w = tid >> 6;
    const int l15 = lane & 15, quad = lane >> 4;

    {   // stage Q * SCALE -> bf16 (qp is fp32)
        const int row = tid >> 2, cg = (tid & 3) * 16;
        const float* qs = qp + ((size_t)(b * 512 + q0 + row)) * DM + h * 64 + cg;
        float4 f[4];
#pragma unroll
        for (int j = 0; j < 4; j++) f[j] = *(const float4*)(qs + j * 4);
        bf16x8 o0, o1;
        o0[0]=(bf16_t)(f[0].x*SCALE_F); o0[1]=(bf16_t)(f[0].y*SCALE_F); o0[2]=(bf16_t)(f[0].z*SCALE_F); o0[3]=(bf16_t)(f[0].w*SCALE_F);
        o0[4]=(bf16_t)(f[1].x*SCALE_F); o0[5]=(bf16_t)(f[1].y*SCALE_F); o0[6]=(bf16_t)(f[1].z*SCALE_F); o0[7]=(bf16_t)(f[1].w*SCALE_F);
        o1[0]=(bf16_t)(f[2].x*SCALE_F); o1[1]=(bf16_t)(f[2].y*SCALE_F); o1[2]=(bf16_t)(f[2].z*SCALE_F); o1[3]=(bf16_t)(f[2].w*SCALE_F);
        o1[4]=(bf16_t)(f[3].x*SCALE_F); o1[5]=(bf16_t)(f[3].y*SCALE_F); o1[6]=(bf16_t)(f[3].z*SCALE_F); o1[7]=(bf16_t)(f[3].w*SCALE_F);
        *(bf16x8*)&Qs[row][cg] = o0;
        *(bf16x8*)&Qs[row][cg + 8] = o1;
    }
    const int rsub = lane >> 3, pch = lane & 7, csw = pch ^ rsub;
    const bf16_t* kptr[4]; bf16_t* klds[4];
#pragma unroll
    for (int j = 0; j < 4; j++) {
        const int rb = w * 32 + j * 8;
        kptr[j] = kp + ((size_t)(b * 4096 + rb + rsub)) * DM + h * 64 + csw * 8;
        klds[j] = (bf16_t*)Ks + rb * 64;
    }
    float mrun[4], lrun[4];
#pragma unroll
    for (int r = 0; r < 4; r++) { mrun[r] = -3.0e38f; lrun[r] = 0.f; }

    for (int kt = 0; kt < 8; kt++) {
        const size_t koff = (size_t)(ksp * 8 + kt) * 128 * DM;
        __syncthreads();
#pragma unroll
        for (int j = 0; j < 4; j++) gl16(kptr[j] + koff, klds[j]);
        __syncthreads();
        const f32x4 zv = {0.f, 0.f, 0.f, 0.f};
        f32x4 sacc[8] = {zv, zv, zv, zv, zv, zv, zv, zv};
#pragma unroll
        for (int kss = 0; kss < 2; kss++) {
            bf16x8 af = *(const bf16x8*)&Qs[w * 16 + l15][kss * 32 + quad * 8];
#pragma unroll
            for (int nf = 0; nf < 8; nf++) {
                const int br = nf * 16 + l15;
                bf16x8 bfv = *(const bf16x8*)(Ks + br * 64 + (((kss << 2) | quad) ^ (br & 7)) * 8);
                sacc[nf] = __builtin_amdgcn_mfma_f32_16x16x32_bf16(af, bfv, sacc[nf], 0, 0, 0);
            }
        }
#pragma unroll
        for (int r = 0; r < 4; r++) {
            float tm = sacc[0][r];
#pragma unroll
            for (int i = 1; i < 8; i++) tm = fmaxf(tm, sacc[i][r]);
#pragma unroll
            for (int off = 1; off < 16; off <<= 1) tm = fmaxf(tm, __shfl_xor(tm, off));
            const float mn = fmaxf(mrun[r], tm);
            float s = 0.f;
#pragma unroll
            for (int i = 0; i < 8; i++) s += __expf(sacc[i][r] - mn);
#pragma unroll
            for (int off = 1; off < 16; off <<= 1) s += __shfl_xor(s, off);
            lrun[r] = lrun[r] * __expf(mrun[r] - mn) + s;
            mrun[r] = mn;
        }
    }
    if (l15 == 0) {
#pragma unroll
        for (int r = 0; r < 4; r++) {
            const int row = q0 + w * 16 + quad * 4 + r;
            mws[((size_t)ksp * 16 + bh) * 512 + row] = mrun[r];
            lws[((size_t)ksp * 16 + bh) * 512 + row] = lrun[r];
        }
    }
}

// ---------------- attention pass 2: recompute S, write P to d_out, fused PV -------------
// KVBLK=128 + NO softmax->PV barrier (Ps rows w*16..w*16+15 are written AND read by the
// same wave -- only intra-wave LDS dependency). 2 barriers / 128 tokens (was 3 / 64).
__global__ __launch_bounds__(256, 2)
void attn_pass2(const float* __restrict__ qp, const bf16_t* __restrict__ kp,
                const bf16_t* __restrict__ vpT, const float* __restrict__ mws,
                const float* __restrict__ lws, float* __restrict__ attn,
                float* __restrict__ xout)
{
    __shared__ bf16_t Qs[64][72];
    __shared__ bf16_t Ks[128 * 64];
    __shared__ bf16_t Vs[64 * 128];
    __shared__ bf16_t Ps[64][136];
    const int fl = (blockIdx.z << 5) | (blockIdx.y << 2) | blockIdx.x;
    const int nfl = ((fl & 7) << 6) | (fl >> 3);
    const int ksp = nfl & 3, qt = (nfl >> 2) & 7, bh = nfl >> 5;
    const int b = bh >> 3, h = bh & 7, q0 = qt * 64;
    const int tid = threadIdx.x, lane = tid & 63, w = tid >> 6;
    const int l15 = lane & 15, quad = lane >> 4;

    {   // stage Q * SCALE
        const int row = tid >> 2, cg = (tid & 3) * 16;
        const float* qs = qp + ((size_t)(b * 512 + q0 + row)) * DM + h * 64 + cg;
        float4 f[4];
#pragma unroll
        for (int j = 0; j < 4; j++) f[j] = *(const float4*)(qs + j * 4);
        bf16x8 o0, o1;
        o0[0]=(bf16_t)(f[0].x*SCALE_F); o0[1]=(bf16_t)(f[0].y*SCALE_F); o0[2]=(bf16_t)(f[0].z*SCALE_F); o0[3]=(bf16_t)(f[0].w*SCALE_F);
        o0[4]=(bf16_t)(f[1].x*SCALE_F); o0[5]=(bf16_t)(f[1].y*SCALE_F); o0[6]=(bf16_t)(f[1].z*SCALE_F); o0[7]=(bf16_t)(f[1].w*SCALE_F);
        o1[0]=(bf16_t)(f[2].x*SCALE_F); o1[1]=(bf16_t)(f[2].y*SCALE_F); o1[2]=(bf16_t)(f[2].z*SCALE_F); o1[3]=(bf16_t)(f[2].w*SCALE_F);
        o1[4]=(bf16_t)(f[3].x*SCALE_F); o1[5]=(bf16_t)(f[3].y*SCALE_F); o1[6]=(bf16_t)(f[3].z*SCALE_F); o1[7]=(bf16_t)(f[3].w*SCALE_F);
        *(bf16x8*)&Qs[row][cg] = o0;
        *(bf16x8*)&Qs[row][cg + 8] = o1;
    }
    // combined stats for my 4 rows
    float mrow[4], linv[4];
#pragma unroll
    for (int r = 0; r < 4; r++) {
        const int row = q0 + w * 16 + quad * 4 + r;
        float mv[4], lv[4], mm = -3.0e38f;
#pragma unroll
        for (int p = 0; p < 4; p++) {
            mv[p] = mws[((size_t)p * 16 + bh) * 512 + row];
            lv[p] = lws[((size_t)p * 16 + bh) * 512 + row];
            mm = fmaxf(mm, mv[p]);
        }
        float ll = 0.f;
#pragma unroll
        for (int p = 0; p < 4; p++) ll += lv[p] * __expf(mv[p] - mm);
        mrow[r] = mm; linv[r] = 1.f / ll;
    }
    // K staging: 128B rows, 8 rows/gl16, row&7 pre-swizzle
    const int rsub = lane >> 3, pch = lane & 7, csw = pch ^ rsub;
    const bf16_t* kptr[4]; bf16_t* klds[4];
#pragma unroll
    for (int j = 0; j < 4; j++) {
        const int rb = w * 32 + j * 8;
        kptr[j] = kp + ((size_t)(b * 4096 + rb + rsub)) * DM + h * 64 + csw * 8;
        klds[j] = (bf16_t*)Ks + rb * 64;
    }
    // V staging: 256B rows (128 tokens), 4 rows/gl16, row&7 pre-swizzle
    const int rsub4 = lane >> 4, pch16 = lane & 15;
    const bf16_t* vptr[4]; bf16_t* vlds[4];
#pragma unroll
    for (int j = 0; j < 4; j++) {
        const int rv = w * 16 + j * 4;   // d-row base (multiple of 4; w*16 ≡ 0 mod 8)
        const int cswv = pch16 ^ (((j & 1) << 2) | rsub4);
        vptr[j] = vpT + ((size_t)(b * DM + h * 64 + rv + rsub4)) * 4096 + cswv * 8;
        vlds[j] = (bf16_t*)Vs + rv * 128;
    }
    const f32x4 zv = {0.f, 0.f, 0.f, 0.f};
    f32x4 oacc[4] = {zv, zv, zv, zv};
    float* ap = attn + ((size_t)bh * 512) * 4096;

    for (int kt = 0; kt < 8; kt++) {
        const int kg = (ksp * 8 + kt) * 128;
        __syncthreads();
#pragma unroll
        for (int j = 0; j < 4; j++) gl16(kptr[j] + (size_t)kg * DM, klds[j]);
#pragma unroll
        for (int j = 0; j < 4; j++) gl16(vptr[j] + kg, vlds[j]);
        __syncthreads();
        f32x4 sacc[8] = {zv, zv, zv, zv, zv, zv, zv, zv};
#pragma unroll
        for (int kss = 0; kss < 2; kss++) {
            bf16x8 af = *(const bf16x8*)&Qs[w * 16 + l15][kss * 32 + quad * 8];
#pragma unroll
            for (int nf = 0; nf < 8; nf++) {
                const int br = nf * 16 + l15;
                bf16x8 bfv = *(const bf16x8*)(Ks + br * 64 + (((kss << 2) | quad) ^ (br & 7)) * 8);
                sacc[nf] = __builtin_amdgcn_mfma_f32_16x16x32_bf16(af, bfv, sacc[nf], 0, 0, 0);
            }
        }
#pragma unroll
        for (int nf = 0; nf < 8; nf++)
#pragma unroll
            for (int r = 0; r < 4; r++) {
                const float p = __expf(sacc[nf][r] - mrow[r]) * linv[r];
                ap[((size_t)(q0 + w * 16 + quad * 4 + r)) * 4096 + kg + nf * 16 + l15] = p;
                Ps[w * 16 + quad * 4 + r][nf * 16 + l15] = (bf16_t)p;
            }
        // no barrier: Ps rows [w*16, w*16+16) are wave-private (write & read by wave w)
#pragma unroll
        for (int kss = 0; kss < 4; kss++) {
            bf16x8 paf = *(const bf16x8*)&Ps[w * 16 + l15][kss * 32 + quad * 8];
#pragma unroll
            for (int nf = 0; nf < 4; nf++) {
                const int br = nf * 16 + l15;
                bf16x8 vb = *(const bf16x8*)(Vs + br * 128 + (((kss << 2) | quad) ^ (br & 7)) * 8);
                oacc[nf] = __builtin_amdgcn_mfma_f32_16x16x32_bf16(paf, vb, oacc[nf], 0, 0, 0);
            }
        }
    }
#pragma unroll
    for (int nf = 0; nf < 4; nf++) {
        const int n = h * 64 + nf * 16 + l15;
#pragma unroll
        for (int r = 0; r < 4; r++) {
            const int m = b * 512 + q0 + w * 16 + quad * 4 + r;
            atomicAdd(&xout[(size_t)m * DM + n], oacc[nf][r]);
        }
    }
}

// ---------------- host ----------------
extern "C" void kernel_launch(void* const* d_in, const int* in_sizes, int n_in,
                              void* d_out, int out_size, void* d_ws, size_t ws_size,
                              hipStream_t stream)
{
    (void)in_sizes; (void)n_in; (void)out_size; (void)ws_size;
    const float* q    = (const float*)d_in[0];
    const float* kv   = (const float*)d_in[1];
    const float* q_gw = (const float*)d_in[2];
    const float* q_gb = (const float*)d_in[3];
    const float* q_w  = (const float*)d_in[4];
    const float* q_b  = (const float*)d_in[5];
    const float* k_gw = (const float*)d_in[6];
    const float* k_gb = (const float*)d_in[7];
    const float* k_w  = (const float*)d_in[8];
    const float* k_b  = (const float*)d_in[9];
    const float* v_gw = (const float*)d_in[10];
    const float* v_gb = (const float*)d_in[11];
    const float* v_w  = (const float*)d_in[12];
    const float* v_b  = (const float*)d_in[13];
    const float* o_gw = (const float*)d_in[14];
    const float* o_gb = (const float*)d_in[15];
    const float* o_w  = (const float*)d_in[16];
    const float* o_b  = (const float*)d_in[17];

    float* out0 = (float*)d_out;
    float* attn = out0 + (size_t)1024 * 512;

    char* ws = (char*)d_ws;
    size_t off = 0;
    auto alloc = [&](size_t bytes) {
        void* p = ws + off;
        off += (bytes + 255) & ~(size_t)255;
        return p;
    };
    bf16_t* Xq    = (bf16_t*)alloc((size_t)1024 * 512 * 2);
    bf16_t* Xkv   = (bf16_t*)alloc((size_t)8192 * 512 * 2);
    bf16_t* Wall  = (bf16_t*)alloc((size_t)4 * NE * 512 * 512 * 2);
    bf16_t* Wq_t  = Wall;
    bf16_t* Wk_t  = Wall + (size_t)1 * NE * 512 * 512;
    bf16_t* Wv_t  = Wall + (size_t)2 * NE * 512 * 512;
    bf16_t* Wo_t  = Wall + (size_t)3 * NE * 512 * 512;
    float*  qpf   = (float*)alloc((size_t)1024 * 512 * 4);   // q-proj fp32 (atomic)
    bf16_t* kp    = (bf16_t*)alloc((size_t)8192 * 512 * 2);
    bf16_t* vpT   = (bf16_t*)alloc((size_t)8192 * 512 * 2);
    float*  xatt  = (float*)alloc((size_t)1024 * 512 * 4);
    bf16_t* xbf   = (bf16_t*)alloc((size_t)1024 * 512 * 2);
    float*  Gq    = (float*)alloc((size_t)1024 * NE * 4);
    float*  Gk    = (float*)alloc((size_t)8192 * NE * 4);
    float*  Gv    = (float*)alloc((size_t)8192 * NE * 4);
    float*  Go    = (float*)alloc((size_t)1024 * NE * 4);
    float*  mws   = (float*)alloc((size_t)4 * 16 * 512 * 4);
    float*  lws   = (float*)alloc((size_t)4 * 16 * 512 * 4);

    cast_bf16_kernel<<<256, 256, 0, stream>>>(q, Xq, 1024 * 512);
    cast_bf16_kernel<<<2048, 256, 0, stream>>>(kv, Xkv, 8192 * 512);
    wtrans4_kernel<<<dim3(16, 16, 4 * NE), 256, 0, stream>>>(q_w, k_w, v_w, o_w, Wall);
    moe_gates<<<1024, 64, 0, stream>>>(q, q_gw, q_gb, Gq);
    moe_gates_kv<<<2048, 256, 0, stream>>>(kv, k_gw, k_gb, v_gw, v_gb, Gk, Gv);

    gate_bias_init<<<2048, 256, 0, stream>>>(Gq, q_b, qpf);
    moe_gemm_split<<<dim3(16, 8, 5), 256, 0, stream>>>(Xq, Wq_t, Gq, qpf);
    moe_gemm_kv<<<dim3(64, 8), 256, 0, stream>>>(Xkv, Wk_t, Wv_t, k_b, v_b, Gk, Gv, kp, vpT);

    attn_pass1<<<dim3(4, 8, 16), 256, 0, stream>>>(qpf, kp, mws, lws);
    hipMemsetAsync(xatt, 0, (size_t)1024 * 512 * 4, stream);
    attn_pass2<<<dim3(4, 8, 16), 256, 0, stream>>>(qpf, kp, vpT, mws, lws, attn, xatt);

    moe_gates<<<1024, 64, 0, stream>>>(xatt, o_gw, o_gb, Go);
    cast_bf16_kernel<<<256, 256, 0, stream>>>(xatt, xbf, 1024 * 512);
    gate_bias_init<<<2048, 256, 0, stream>>>(Go, o_b, out0);
    moe_gemm_split<<<dim3(16, 8, 5), 256, 0, stream>>>(xbf, Wo_t, Go, out0);
}